// Round 13
// baseline (1970.534 us; speedup 1.0000x reference)
//
#include <hip/hip_runtime.h>

typedef __attribute__((ext_vector_type(8))) __bf16 bf16x8;
typedef __attribute__((ext_vector_type(4))) float f32x4;
typedef __attribute__((ext_vector_type(4))) unsigned int u32x4;
typedef __attribute__((ext_vector_type(2))) unsigned int u32x2;

__device__ __forceinline__ unsigned short f2bf(float f) {
  unsigned int u = __float_as_uint(f);
  u += 0x7fffu + ((u >> 16) & 1u);   // RNE
  return (unsigned short)(u >> 16);
}

__device__ __forceinline__ void gload16(const void* g, void* l) {
  __builtin_amdgcn_global_load_lds(
      (const __attribute__((address_space(1))) unsigned int*)g,
      (__attribute__((address_space(3))) unsigned int*)l, 16, 0, 0);
}

// ------------- fused embedding + LN (layer-0 LN1): x out f32, hb out bf16 ----
__global__ __launch_bounds__(256) void embed_ln_k(const int* __restrict__ idx,
    const float* __restrict__ tok, const float* __restrict__ pos,
    const float* __restrict__ g, const float* __restrict__ bta,
    float* __restrict__ x, unsigned short* __restrict__ out) {
  __shared__ float red[4];
  int row = blockIdx.x, tid = threadIdx.x;
  int t = row & 1023;
  int c = tid << 2;
  int id = idx[row];
  f32x4 xv = *(const f32x4*)(tok + ((size_t)id << 10) + c);
  f32x4 p = *(const f32x4*)(pos + ((size_t)t << 10) + c);
  xv += p;
  *(f32x4*)(x + ((size_t)row << 10) + c) = xv;
  float s = xv[0] + xv[1] + xv[2] + xv[3];
  #pragma unroll
  for (int off = 32; off; off >>= 1) s += __shfl_xor(s, off);
  if ((tid & 63) == 0) red[tid >> 6] = s;
  __syncthreads();
  float mean = (red[0] + red[1] + red[2] + red[3]) * (1.f / 1024.f);
  __syncthreads();
  f32x4 d = xv - mean;
  float s2 = d[0]*d[0] + d[1]*d[1] + d[2]*d[2] + d[3]*d[3];
  #pragma unroll
  for (int off = 32; off; off >>= 1) s2 += __shfl_xor(s2, off);
  if ((tid & 63) == 0) red[tid >> 6] = s2;
  __syncthreads();
  float var = (red[0] + red[1] + red[2] + red[3]) * (1.f / 1024.f);
  float rs = rsqrtf(var + 1e-5f);
  f32x4 gv = *(const f32x4*)(g + c);
  f32x4 bv = *(const f32x4*)(bta + c);
  unsigned int p0 = (unsigned int)f2bf(d[0]*rs*gv[0] + bv[0]) |
                    ((unsigned int)f2bf(d[1]*rs*gv[1] + bv[1]) << 16);
  unsigned int p1 = (unsigned int)f2bf(d[2]*rs*gv[2] + bv[2]) |
                    ((unsigned int)f2bf(d[3]*rs*gv[3] + bv[3]) << 16);
  u32x2 o; o[0] = p0; o[1] = p1;
  *(u32x2*)(out + ((size_t)row << 10) + c) = o;
}

// ---------------- layernorm (f32 in, bf16 out) — small-ws fallback ----------
__global__ __launch_bounds__(256) void ln_k(const float* __restrict__ x,
    const float* __restrict__ g, const float* __restrict__ bta,
    unsigned short* __restrict__ out) {
  __shared__ float red[4];
  int row = blockIdx.x, tid = threadIdx.x;
  const float* xr = x + ((size_t)row << 10);
  f32x4 xv = *(const f32x4*)(xr + (tid << 2));
  float s = xv[0] + xv[1] + xv[2] + xv[3];
  #pragma unroll
  for (int off = 32; off; off >>= 1) s += __shfl_xor(s, off);
  if ((tid & 63) == 0) red[tid >> 6] = s;
  __syncthreads();
  float mean = (red[0] + red[1] + red[2] + red[3]) * (1.f / 1024.f);
  __syncthreads();
  f32x4 d = xv - mean;
  float s2 = d[0]*d[0] + d[1]*d[1] + d[2]*d[2] + d[3]*d[3];
  #pragma unroll
  for (int off = 32; off; off >>= 1) s2 += __shfl_xor(s2, off);
  if ((tid & 63) == 0) red[tid >> 6] = s2;
  __syncthreads();
  float var = (red[0] + red[1] + red[2] + red[3]) * (1.f / 1024.f);
  float rs = rsqrtf(var + 1e-5f);
  f32x4 gv = *(const f32x4*)(g + (tid << 2));
  f32x4 bv = *(const f32x4*)(bta + (tid << 2));
  unsigned int p0 = (unsigned int)f2bf(d[0]*rs*gv[0] + bv[0]) |
                    ((unsigned int)f2bf(d[1]*rs*gv[1] + bv[1]) << 16);
  unsigned int p1 = (unsigned int)f2bf(d[2]*rs*gv[2] + bv[2]) |
                    ((unsigned int)f2bf(d[3]*rs*gv[3] + bv[3]) << 16);
  u32x2 o; o[0] = p0; o[1] = p1;
  *(u32x2*)(out + ((size_t)row << 10) + (tid << 2)) = o;
}

// ---------------- weight transpose: f32 [R][C] -> bf16 [C][R] ----------------
__global__ __launch_bounds__(256) void transp_k(const float* __restrict__ in,
    unsigned short* __restrict__ out, int R, int C) {
  __shared__ unsigned short tile[64 * 65];
  size_t lay = (size_t)blockIdx.z * R * C;
  int c0 = blockIdx.x << 6, r0 = blockIdx.y << 6;
  int t = threadIdx.x;
  #pragma unroll
  for (int i = 0; i < 4; i++) {
    int e = (i << 10) + (t << 2);
    int r = e >> 6, c = e & 63;
    f32x4 v = *(const f32x4*)(in + lay + (size_t)(r0 + r) * C + c0 + c);
    tile[r * 65 + c]     = f2bf(v[0]);
    tile[r * 65 + c + 1] = f2bf(v[1]);
    tile[r * 65 + c + 2] = f2bf(v[2]);
    tile[r * 65 + c + 3] = f2bf(v[3]);
  }
  __syncthreads();
  #pragma unroll
  for (int i = 0; i < 4; i++) {
    int e = (i << 10) + (t << 2);
    int cc = e >> 6, rr = e & 63;
    unsigned int a0 = tile[(rr + 0) * 65 + cc];
    unsigned int a1 = tile[(rr + 1) * 65 + cc];
    unsigned int a2 = tile[(rr + 2) * 65 + cc];
    unsigned int a3 = tile[(rr + 3) * 65 + cc];
    u32x2 pk; pk[0] = a0 | (a1 << 16); pk[1] = a2 | (a3 << 16);
    *(u32x2*)(out + lay + (size_t)(c0 + cc) * R + r0 + rr) = pk;
  }
}

// ---- batched 1024x1024 transpose: z = which*8 + layer (wq/wk/wv/wp) ----
__global__ __launch_bounds__(256) void transp4_k(
    const float* __restrict__ w0, const float* __restrict__ w1,
    const float* __restrict__ w2, const float* __restrict__ w3,
    unsigned short* __restrict__ o0, unsigned short* __restrict__ o1,
    unsigned short* __restrict__ o2, unsigned short* __restrict__ o3) {
  __shared__ unsigned short tile[64 * 65];
  int z = blockIdx.z;
  int which = z >> 3;
  size_t lay = (size_t)(z & 7) << 20;
  const float* in = which == 0 ? w0 : which == 1 ? w1 : which == 2 ? w2 : w3;
  unsigned short* out = which == 0 ? o0 : which == 1 ? o1 : which == 2 ? o2 : o3;
  int c0 = blockIdx.x << 6, r0 = blockIdx.y << 6;
  int t = threadIdx.x;
  #pragma unroll
  for (int i = 0; i < 4; i++) {
    int e = (i << 10) + (t << 2);
    int r = e >> 6, c = e & 63;
    f32x4 v = *(const f32x4*)(in + lay + (size_t)((r0 + r) << 10) + c0 + c);
    tile[r * 65 + c]     = f2bf(v[0]);
    tile[r * 65 + c + 1] = f2bf(v[1]);
    tile[r * 65 + c + 2] = f2bf(v[2]);
    tile[r * 65 + c + 3] = f2bf(v[3]);
  }
  __syncthreads();
  #pragma unroll
  for (int i = 0; i < 4; i++) {
    int e = (i << 10) + (t << 2);
    int cc = e >> 6, rr = e & 63;
    unsigned int a0 = tile[(rr + 0) * 65 + cc];
    unsigned int a1 = tile[(rr + 1) * 65 + cc];
    unsigned int a2 = tile[(rr + 2) * 65 + cc];
    unsigned int a3 = tile[(rr + 3) * 65 + cc];
    u32x2 pk; pk[0] = a0 | (a1 << 16); pk[1] = a2 | (a3 << 16);
    *(u32x2*)(out + lay + (size_t)((c0 + cc) << 10) + r0 + rr) = pk;
  }
}

// ============ 256x256 8-phase GEMM (round-8 proven: 396us, MfmaUtil 28%) ======
// BK=64, 128KB LDS, 1 block/CU. Frag-reuse quadrant path. PARKED.
#define VMC6 asm volatile("s_waitcnt vmcnt(6)" ::: "memory")
#define VMC8 asm volatile("s_waitcnt vmcnt(8)" ::: "memory")
#define VMC2 asm volatile("s_waitcnt vmcnt(2)" ::: "memory")
#define VMC0 asm volatile("s_waitcnt vmcnt(0)" ::: "memory")

__global__ __launch_bounds__(512, 2) void gemm256_k(
    const unsigned short* __restrict__ A, const unsigned short* __restrict__ Bt,
    const float* __restrict__ bias, float* __restrict__ o32,
    unsigned short* __restrict__ obf, int M, int N, int K, int relu) {
  __shared__ unsigned short lds[2][2][2][8192];
  int mb = M >> 8;
  int wg = blockIdx.x, nwg = gridDim.x;
  int cpx = nwg >> 3;
  int swz = (wg & 7) * cpx + (wg >> 3);      // nwg % 8 == 0
  int bm = swz % mb, bn = swz / mb;          // bm fast: per-XCD bn-stripes
  int m0 = bm << 8, n0 = bn << 8;
  int tid = threadIdx.x, lane = tid & 63, wave = tid >> 6;
  int wrow = wave >> 2, wcol = wave & 3;
  int lrow = lane & 15, g4 = lane >> 4, l7 = lane & 7;
  f32x4 acc[8][4] = {};
  bf16x8 af[8], bfv[4];
  const unsigned short* Ag = A + (size_t)m0 * K;
  const unsigned short* Bg = Bt + (size_t)n0 * K;
  auto stage = [&](int op, int b, int h, int kt) {
    const unsigned short* gb = (op ? Bg : Ag) + ((size_t)(h << 7)) * K + kt;
    char* lb = (char*)&lds[op][b][h][0];
    #pragma unroll
    for (int g = 0; g < 2; g++) {
      int row = (g << 6) + (wave << 3) + (lane >> 3);
      int klog = ((lane & 7) ^ ((lane >> 3) & 7)) << 3;   // shorts
      gload16(gb + (size_t)row * K + klog, lb + (g << 13) + (wave << 10));
    }
  };

#define PH(bi, qa, qb, LA, LB, STG, VM)                                        \
  {                                                                            \
    if (LA) {                                                                  \
      const unsigned short* Ah = &lds[0][bi][qa][0];                           \
      _Pragma("unroll")                                                        \
      for (int i = 0; i < 4; i++) {                                            \
        int rl = (wrow << 6) + (i << 4) + lrow;                                \
        af[i*2+0] = *(const bf16x8*)(Ah + rl * 64 + ((g4 ^ l7) << 3));         \
        af[i*2+1] = *(const bf16x8*)(Ah + rl * 64 + (((4 + g4) ^ l7) << 3));   \
      }                                                                        \
    }                                                                          \
    if (LB) {                                                                  \
      const unsigned short* Bh = &lds[1][bi][qb][0];                           \
      _Pragma("unroll")                                                        \
      for (int j = 0; j < 2; j++) {                                            \
        int cl = (wcol << 5) + (j << 4) + lrow;                                \
        bfv[j*2+0] = *(const bf16x8*)(Bh + cl * 64 + ((g4 ^ l7) << 3));        \
        bfv[j*2+1] = *(const bf16x8*)(Bh + cl * 64 + (((4 + g4) ^ l7) << 3));  \
      }                                                                        \
    }                                                                          \
    STG;                                                                       \
    __builtin_amdgcn_s_barrier();                                              \
    asm volatile("s_waitcnt lgkmcnt(0)" ::: "memory");                         \
    __builtin_amdgcn_sched_barrier(0);                                         \
    __builtin_amdgcn_s_setprio(1);                                             \
    _Pragma("unroll")                                                          \
    for (int i = 0; i < 4; i++)                                                \
      _Pragma("unroll")                                                        \
      for (int j = 0; j < 2; j++) {                                            \
        acc[(qa)*4+i][(qb)*2+j] = __builtin_amdgcn_mfma_f32_16x16x32_bf16(     \
            af[i*2+0], bfv[j*2+0], acc[(qa)*4+i][(qb)*2+j], 0, 0, 0);          \
        acc[(qa)*4+i][(qb)*2+j] = __builtin_amdgcn_mfma_f32_16x16x32_bf16(     \
            af[i*2+1], bfv[j*2+1], acc[(qa)*4+i][(qb)*2+j], 0, 0, 0);          \
      }                                                                        \
    __builtin_amdgcn_s_setprio(0);                                             \
    VM;                                                                        \
    __builtin_amdgcn_s_barrier();                                              \
  }

  int nt = K >> 6;          // K-tiles; nt even (K%128==0)
  int nit = nt >> 1;
  stage(0, 0, 0, 0); stage(1, 0, 0, 0); stage(1, 0, 1, 0); stage(0, 0, 1, 0);
  stage(0, 1, 0, 64);
  VMC2;
  __builtin_amdgcn_s_barrier();
  for (int it = 0; it < nit; ++it) {
    int kT1 = ((it << 1) + 1) << 6;
    int kT2 = ((it << 1) + 2) << 6;
    int kT3 = ((it << 1) + 3) << 6;
    bool m2 = (it + 1) < nit;
    PH(0, 0, 0, 1, 1, { stage(1, 1, 1, kT1); stage(1, 1, 0, kT1); }, )
    PH(0, 0, 1, 0, 1, { stage(0, 1, 1, kT1); }, )
    PH(0, 1, 1, 1, 0, if (m2) { stage(0, 0, 0, kT2); }, )
    PH(0, 1, 0, 0, 1, if (m2) { stage(1, 0, 1, kT2); },
       if (m2) { VMC6; } else { VMC2; })
    PH(1, 0, 0, 1, 1, if (m2) { stage(1, 0, 0, kT2); }, )
    PH(1, 0, 1, 0, 1, if (m2) { stage(0, 0, 1, kT2); },
       if (m2) { VMC8; } else { VMC0; })
    PH(1, 1, 1, 1, 0, if (m2) { stage(0, 1, 0, kT3); }, )
    PH(1, 1, 0, 0, 1, , if (m2) { VMC2; })
  }
#undef PH
  int frow = g4 << 2;
  #pragma unroll
  for (int rt = 0; rt < 8; rt++) {
    int qa = rt >> 2, i = rt & 3;
    int grow = m0 + (qa << 7) + (wrow << 6) + (i << 4) + frow;
    #pragma unroll
    for (int ct = 0; ct < 4; ct++) {
      int qb = ct >> 1, j = ct & 1;
      int gcol = n0 + (qb << 7) + (wcol << 5) + (j << 4) + lrow;
      float bb = bias ? bias[gcol] : 0.f;
      f32x4 av = acc[rt][ct];
      #pragma unroll
      for (int r = 0; r < 4; r++) {
        float vv = av[r] + bb;
        if (relu) vv = fmaxf(vv, 0.f);
        if (o32) o32[(size_t)(grow + r) * N + gcol] = vv;
        else obf[(size_t)(grow + r) * N + gcol] = f2bf(vv);
      }
    }
  }
}

// ---------------- m97-structure GEMM (layer GEMMs) ----------------
__global__ __launch_bounds__(256) void gemm_bt(
    const unsigned short* __restrict__ A,
    const unsigned short* __restrict__ Bt0, const unsigned short* __restrict__ Bt1,
    const unsigned short* __restrict__ Bt2,
    const float* __restrict__ bias, const float* resid,
    unsigned short* __restrict__ ob0, unsigned short* __restrict__ ob1,
    unsigned short* __restrict__ vtout, float* o32,
    int M, int N, int K, int relu) {
  __shared__ unsigned short As[128 * 64];
  __shared__ unsigned short Bs[128 * 64];
  int nbp = N >> 7;
  int which = blockIdx.x / nbp;
  int bx = blockIdx.x - which * nbp;
  const unsigned short* Bt = which == 0 ? Bt0 : (which == 1 ? Bt1 : Bt2);
  int m0 = blockIdx.y << 7, n0 = bx << 7;
  int tid = threadIdx.x, lane = tid & 63, wave = tid >> 6;
  int wr = (wave >> 1) << 6, wc = (wave & 1) << 6;
  int lrow = lane & 15, lk8 = (lane >> 4) << 3;
  int wbase = wave << 12;
  f32x4 acc[4][4] = {};
  const unsigned short* Ag = A + (size_t)m0 * K;
  const unsigned short* Bg = Bt + (size_t)n0 * K;
  for (int k0 = 0; k0 < K; k0 += 64) {
    #pragma unroll
    for (int i = 0; i < 4; i++) {
      int o = wbase + (i << 10) + (lane << 4);
      int r = o >> 7, c = (o & 127) >> 1;
      gload16(Ag + (size_t)r * K + k0 + c, (char*)As + wbase + (i << 10));
      gload16(Bg + (size_t)r * K + k0 + c, (char*)Bs + wbase + (i << 10));
    }
    __syncthreads();
    #pragma unroll
    for (int ks = 0; ks < 2; ks++) {
      bf16x8 af[4], bfv[4];
      #pragma unroll
      for (int i = 0; i < 4; i++)
        af[i] = *(const bf16x8*)(As + ((wr + (i << 4) + lrow) << 6) + (ks << 5) + lk8);
      #pragma unroll
      for (int i = 0; i < 4; i++)
        bfv[i] = *(const bf16x8*)(Bs + ((wc + (i << 4) + lrow) << 6) + (ks << 5) + lk8);
      #pragma unroll
      for (int mi = 0; mi < 4; mi++)
        #pragma unroll
        for (int ni = 0; ni < 4; ni++)
          acc[mi][ni] = __builtin_amdgcn_mfma_f32_16x16x32_bf16(af[mi], bfv[ni], acc[mi][ni], 0, 0, 0);
    }
    __syncthreads();
  }
  int fr = (lane >> 4) << 2;
  #pragma unroll
  for (int mi = 0; mi < 4; mi++) {
    #pragma unroll
    for (int ni = 0; ni < 4; ni++) {
      int row = m0 + wr + (mi << 4) + fr;
      int col = n0 + wc + (ni << 4) + lrow;
      f32x4 av = acc[mi][ni];
      if (bias) {
        float bb = bias[col];
        av[0] += bb; av[1] += bb; av[2] += bb; av[3] += bb;
      }
      if (relu) {
        av[0] = fmaxf(av[0], 0.f); av[1] = fmaxf(av[1], 0.f);
        av[2] = fmaxf(av[2], 0.f); av[3] = fmaxf(av[3], 0.f);
      }
      if (which == 2) {
        u32x2 pk;
        pk[0] = (unsigned int)f2bf(av[0]) | ((unsigned int)f2bf(av[1]) << 16);
        pk[1] = (unsigned int)f2bf(av[2]) | ((unsigned int)f2bf(av[3]) << 16);
        *(u32x2*)(vtout + (((size_t)(row >> 10) * 16 + (col >> 6)) * 64 + (col & 63)) * 1024
                  + (row & 1023)) = pk;
      } else if (o32) {
        #pragma unroll
        for (int r = 0; r < 4; r++) {
          size_t off = (size_t)(row + r) * N + col;
          float vvv = av[r];
          if (resid) vvv += resid[off];
          o32[off] = vvv;
        }
      } else {
        unsigned short* ob = which == 0 ? ob0 : ob1;
        #pragma unroll
        for (int r = 0; r < 4; r++)
          ob[(size_t)(row + r) * N + col] = f2bf(av[r]);
      }
    }
  }
}

// ---------------- split-K GEMM: partial f32, no epilogue ----------------
__global__ __launch_bounds__(256) void gemm_splitk(
    const unsigned short* __restrict__ A, const unsigned short* __restrict__ Bt,
    float* __restrict__ pbuf, int M, int N, int K, int KS) {
  __shared__ unsigned short As[128 * 64];
  __shared__ unsigned short Bs[128 * 64];
  int m0 = blockIdx.y << 7, n0 = blockIdx.x << 7;
  int kz = blockIdx.z * KS;
  int tid = threadIdx.x, lane = tid & 63, wave = tid >> 6;
  int wr = (wave >> 1) << 6, wc = (wave & 1) << 6;
  int lrow = lane & 15, lk8 = (lane >> 4) << 3;
  int wbase = wave << 12;
  f32x4 acc[4][4] = {};
  const unsigned short* Ag = A + (size_t)m0 * K;
  const unsigned short* Bg = Bt + (size_t)n0 * K;
  for (int k0 = kz; k0 < kz + KS; k0 += 64) {
    #pragma unroll
    for (int i = 0; i < 4; i++) {
      int o = wbase + (i << 10) + (lane << 4);
      int r = o >> 7, c = (o & 127) >> 1;
      gload16(Ag + (size_t)r * K + k0 + c, (char*)As + wbase + (i << 10));
      gload16(Bg + (size_t)r * K + k0 + c, (char*)Bs + wbase + (i << 10));
    }
    __syncthreads();
    #pragma unroll
    for (int ks = 0; ks < 2; ks++) {
      bf16x8 af[4], bfv[4];
      #pragma unroll
      for (int i = 0; i < 4; i++)
        af[i] = *(const bf16x8*)(As + ((wr + (i << 4) + lrow) << 6) + (ks << 5) + lk8);
      #pragma unroll
      for (int i = 0; i < 4; i++)
        bfv[i] = *(const bf16x8*)(Bs + ((wc + (i << 4) + lrow) << 6) + (ks << 5) + lk8);
      #pragma unroll
      for (int mi = 0; mi < 4; mi++)
        #pragma unroll
        for (int ni = 0; ni < 4; ni++)
          acc[mi][ni] = __builtin_amdgcn_mfma_f32_16x16x32_bf16(af[mi], bfv[ni], acc[mi][ni], 0, 0, 0);
    }
    __syncthreads();
  }
  int fr = (lane >> 4) << 2;
  float* pb = pbuf + (size_t)blockIdx.z * M * N;
  #pragma unroll
  for (int mi = 0; mi < 4; mi++)
    #pragma unroll
    for (int ni = 0; ni < 4; ni++) {
      int row = m0 + wr + (mi << 4) + fr;
      int col = n0 + wc + (ni << 4) + lrow;
      #pragma unroll
      for (int r = 0; r < 4; r++)
        pb[(size_t)(row + r) * N + col] = acc[mi][ni][r];
    }
}

// ---- fused: x += bias + sum_z pbuf[z]; out = LN(x_new) (bf16). N=1024 ----
__global__ __launch_bounds__(256) void reduce_ln_k(float* __restrict__ x,
    const float* __restrict__ pbuf, const float* __restrict__ bias, int nz,
    const float* __restrict__ g, const float* __restrict__ bta,
    unsigned short* __restrict__ out) {
  __shared__ float red[4];
  int row = blockIdx.x, tid = threadIdx.x;
  int c = tid << 2;
  size_t off = ((size_t)row << 10) + c;
  f32x4 s = *(const f32x4*)(bias + c);
  for (int z = 0; z < nz; z++)
    s += *(const f32x4*)(pbuf + ((size_t)z << 21) + off);
  f32x4 xv = *(const f32x4*)(x + off);
  xv += s;
  *(f32x4*)(x + off) = xv;
  float sm = xv[0] + xv[1] + xv[2] + xv[3];
  #pragma unroll
  for (int o = 32; o; o >>= 1) sm += __shfl_xor(sm, o);
  if ((tid & 63) == 0) red[tid >> 6] = sm;
  __syncthreads();
  float mean = (red[0] + red[1] + red[2] + red[3]) * (1.f / 1024.f);
  __syncthreads();
  f32x4 d = xv - mean;
  float s2 = d[0]*d[0] + d[1]*d[1] + d[2]*d[2] + d[3]*d[3];
  #pragma unroll
  for (int o = 32; o; o >>= 1) s2 += __shfl_xor(s2, o);
  if ((tid & 63) == 0) red[tid >> 6] = s2;
  __syncthreads();
  float var = (red[0] + red[1] + red[2] + red[3]) * (1.f / 1024.f);
  float rs = rsqrtf(var + 1e-5f);
  f32x4 gv = *(const f32x4*)(g + c);
  f32x4 bv = *(const f32x4*)(bta + c);
  unsigned int p0 = (unsigned int)f2bf(d[0]*rs*gv[0] + bv[0]) |
                    ((unsigned int)f2bf(d[1]*rs*gv[1] + bv[1]) << 16);
  unsigned int p1 = (unsigned int)f2bf(d[2]*rs*gv[2] + bv[2]) |
                    ((unsigned int)f2bf(d[3]*rs*gv[3] + bv[3]) << 16);
  u32x2 o2; o2[0] = p0; o2[1] = p1;
  *(u32x2*)(out + ((size_t)row << 10) + c) = o2;
}

// ------- windowed flash attention, KVBLK=64, 4 waves, K/V double-buffered ----
// Exact defer-max (T13, THR=0, BIT-IDENTICAL): if all lanes' local max <= m_,
// the wave max is <= m_ so nm==m_ and sca==1 -> skip the shfl max-tree, the
// sca exp, l_ scale and all 16 o_ rescale mults (wave-uniform branch).
__global__ __launch_bounds__(256) void attn64_k(
    const unsigned short* __restrict__ q, const unsigned short* __restrict__ k,
    const unsigned short* __restrict__ vt, unsigned short* __restrict__ att) {
  __shared__ unsigned short Ks[2][64 * 72];  // [buf][s][hd]
  __shared__ unsigned short Vs[2][64 * 72];  // [buf][hd][s]
  __shared__ unsigned short Ps[4][16 * 72];  // per-wave [row][s]
  int t0 = (15 - (int)blockIdx.x) << 6;      // LPT: heavy blocks first
  int h = blockIdx.y, b = blockIdx.z;
  int tid = threadIdx.x, lane = tid & 63, w = tid >> 6;
  int lrow = lane & 15, lk8 = (lane >> 4) << 3, fr = (lane >> 4) << 2;
  int qrow = t0 + (w << 4) + lrow;
  size_t qoff = ((size_t)((b << 10) + qrow) << 10) + (h << 6);
  bf16x8 a0 = *(const bf16x8*)(q + qoff + lk8);
  bf16x8 a1 = *(const bf16x8*)(q + qoff + 32 + lk8);
  float m_[4] = {-1e30f, -1e30f, -1e30f, -1e30f};
  float l_[4] = {0.f, 0.f, 0.f, 0.f};
  f32x4 o_[4] = {};
  int s_lo = (511 - ((t0 + 63) >> 1)) & ~63;
  int s_hi = 511 + ((t0 + 64) >> 1);
  int s_end = (s_hi + 64) & ~63;             // exclusive, <=1024
  int krow = tid >> 2, kc = (tid & 3) << 4;  // 4 thr/row, 16 shorts each
  size_t vbase = ((size_t)((b << 4) + h) << 16) + ((size_t)krow << 10);
  unsigned short* Psw = &Ps[w][0];
  u32x4 kv0, kv1, vv0, vv1;
  auto loadT = [&](int s0) {
    size_t koff = (((size_t)((b << 10) + s0 + krow)) << 10) + (h << 6) + kc;
    kv0 = *(const u32x4*)(k + koff);
    kv1 = *(const u32x4*)(k + koff + 8);
    vv0 = *(const u32x4*)(vt + vbase + s0 + kc);
    vv1 = *(const u32x4*)(vt + vbase + s0 + kc + 8);
  };
  loadT(s_lo);
  int buf = 0;
  for (int s0 = s_lo; s0 < s_end; s0 += 64) {
    unsigned short* Kb = &Ks[buf][0];
    unsigned short* Vb = &Vs[buf][0];
    *(u32x4*)(Kb + krow * 72 + kc) = kv0;
    *(u32x4*)(Kb + krow * 72 + kc + 8) = kv1;
    *(u32x4*)(Vb + krow * 72 + kc) = vv0;
    *(u32x4*)(Vb + krow * 72 + kc + 8) = vv1;
    __syncthreads();
    if (s0 + 64 < s_end) loadT(s0 + 64);     // overlap with compute below
    f32x4 sc[4];
    #pragma unroll
    for (int sb = 0; sb < 4; sb++) {
      f32x4 z = {};
      bf16x8 kb0 = *(const bf16x8*)(Kb + ((sb << 4) + lrow) * 72 + lk8);
      bf16x8 kb1 = *(const bf16x8*)(Kb + ((sb << 4) + lrow) * 72 + 32 + lk8);
      z = __builtin_amdgcn_mfma_f32_16x16x32_bf16(a0, kb0, z, 0, 0, 0);
      z = __builtin_amdgcn_mfma_f32_16x16x32_bf16(a1, kb1, z, 0, 0, 0);
      sc[sb] = z;
    }
    #pragma unroll
    for (int r = 0; r < 4; r++) {
      int t = t0 + (w << 4) + fr + r;
      int lov = 511 - (t >> 1), hiv = 511 + ((t + 1) >> 1);
      float px[4];
      float tm = -1e30f;
      #pragma unroll
      for (int sb = 0; sb < 4; sb++) {
        int sX = s0 + (sb << 4) + lrow;
        bool vX = (sX >= lov) && (sX <= hiv);
        float x = vX ? sc[sb][r] * 0.125f : -1e30f;
        px[sb] = x;
        tm = fmaxf(tm, x);
      }
      float nm = m_[r];
      if (!__all(tm <= m_[r])) {             // max grew somewhere in the wave
        #pragma unroll
        for (int off = 8; off; off >>= 1) tm = fmaxf(tm, __shfl_xor(tm, off));
        nm = fmaxf(m_[r], tm);
        float sca = __expf(m_[r] - nm);
        m_[r] = nm;
        l_[r] *= sca;
        #pragma unroll
        for (int nb = 0; nb < 4; nb++) o_[nb][r] *= sca;
      }
      float ps = 0.f;
      #pragma unroll
      for (int sb = 0; sb < 4; sb++) {
        float pv = __expf(px[sb] - nm);   // invalid -> exp(-inf) = 0
        ps += pv;
        Psw[(fr + r) * 72 + (sb << 4) + lrow] = f2bf(pv);
      }
      #pragma unroll
      for (int off = 8; off; off >>= 1) ps += __shfl_xor(ps, off);
      l_[r] += ps;
    }
    bf16x8 pa0 = *(const bf16x8*)(Psw + lrow * 72 + lk8);
    bf16x8 pa1 = *(const bf16x8*)(Psw + lrow * 72 + 32 + lk8);
    #pragma unroll
    for (int nb = 0; nb < 4; nb++) {
      bf16x8 vb0 = *(const bf16x8*)(Vb + ((nb << 4) + lrow) * 72 + lk8);
      bf16x8 vb1 = *(const bf16x8*)(Vb + ((nb << 4) + lrow) * 72 + 32 + lk8);
      o_[nb] = __builtin_amdgcn_mfma_f32_16x16x32_bf16(pa0, vb0, o_[nb], 0, 0, 0);
      o_[nb] = __builtin_amdgcn_mfma_f32_16x16x32_bf16(pa1, vb1, o_[nb], 0, 0, 0);
    }
    buf ^= 1;
  }
  #pragma unroll
  for (int nb = 0; nb < 4; nb++)
    #pragma unroll
    for (int r = 0; r < 4; r++) {
      float ov = o_[nb][r] / l_[r];
      att[((size_t)((b << 10) + t0 + (w << 4) + fr + r) << 10) + (h << 6) + (nb << 4) + lrow]
          = f2bf(ov);
    }
}

extern "C" void kernel_launch(void* const* d_in, const int* in_sizes, int n_in,
                              void* d_out, int out_size, void* d_ws, size_t ws_size,
                              hipStream_t stream) {
  (void)in_sizes; (void)n_in; (void)out_size;
  const int*   idx  = (const int*)d_in[0];
  const float* tok  = (const float*)d_in[1];
  const float* pos  = (const float*)d_in[2];
  const float* ln1g = (const float*)d_in[3];
  const float* ln1b = (const float*)d_in[4];
  const float* wq   = (const float*)d_in[5];
  const float* wk   = (const float*)d_in[6];
  const float* wv   = (const float*)d_in[7];
  const float* wpj  = (const float*)d_in[8];
  const float* bpj  = (const float*)d_in[9];
  const float* ln2g = (const float*)d_in[10];
  const float* ln2b = (const float*)d_in[11];
  const float* w1   = (const float*)d_in[12];
  const float* b1   = (const float*)d_in[13];
  const float* w2   = (const float*)d_in[14];
  const float* b2   = (const float*)d_in[15];
  const float* lnfg = (const float*)d_in[16];
  const float* lnfb = (const float*)d_in[17];
  const float* wlm  = (const float*)d_in[18];
  const float* blm  = (const float*)d_in[19];
  float* out = (float*)d_out;

  char* ws = (char*)d_ws;
  const size_t MB = 1u << 20;
  float*          x    = (float*)ws;
  unsigned short* hb   = (unsigned short*)(ws + 8 * MB);
  unsigned short* qb   = (unsigned short*)(ws + 12 * MB);
  unsigned short* kb   = (unsigned short*)(ws + 16 * MB);
  unsigned short* vbuf = (unsigned short*)(ws + 20 * MB);
  unsigned short* ab   = (unsigned short*)(ws + 24 * MB);
  unsigned short* m1   = (unsigned short*)(ws + 28 * MB);
  const int M = 2048, D = 1024;

  int nz; float* pb; bool bigp;
  if (ws_size >= 408 * MB) { nz = 4; pb = (float*)(ws + 376 * MB); bigp = true; }
  else                     { nz = 2; pb = (float*)(ws + 12 * MB); bigp = false; }

  unsigned short* wqT  = (unsigned short*)(ws + 44 * MB);
  unsigned short* wkT  = (unsigned short*)(ws + 60 * MB);
  unsigned short* wvT  = (unsigned short*)(ws + 76 * MB);
  unsigned short* wpT  = (unsigned short*)(ws + 92 * MB);
  unsigned short* w1T  = (unsigned short*)(ws + 108 * MB);
  unsigned short* w2T  = (unsigned short*)(ws + 172 * MB);
  unsigned short* wlmT = (unsigned short*)(ws + 236 * MB);
  transp4_k<<<dim3(16, 16, 32), 256, 0, stream>>>(wq, wk, wv, wpj,
      wqT, wkT, wvT, wpT);
  transp_k<<<dim3(64, 16, 8), 256, 0, stream>>>(w1,   w1T,  1024, 4096);
  transp_k<<<dim3(16, 64, 8), 256, 0, stream>>>(w2,   w2T,  4096, 1024);
  transp_k<<<dim3(1000, 16, 1), 256, 0, stream>>>(wlm, wlmT, 1024, 64000);

  embed_ln_k<<<2048, 256, 0, stream>>>(idx, tok, pos, ln1g, ln1b, x, hb);
  for (int l = 0; l < 8; l++) {
    size_t wo = (size_t)l << 20;
    gemm_bt<<<dim3(24, 16), 256, 0, stream>>>(hb, wqT + wo, wkT + wo, wvT + wo,
        nullptr, nullptr, qb, kb, vbuf, nullptr, M, D, D, 0);
    attn64_k<<<dim3(16, 16, 2), 256, 0, stream>>>(qb, kb, vbuf, ab);
    if (bigp) {
      gemm_splitk<<<dim3(8, 16, 2), 256, 0, stream>>>(ab, wpT + wo,
          pb, M, D, D, D / 2);
      reduce_ln_k<<<2048, 256, 0, stream>>>(x, pb, bpj + l*D, 2,
          ln2g + l*D, ln2b + l*D, hb);
    } else {
      gemm_bt<<<dim3(8, 16), 256, 0, stream>>>(ab, wpT + wo, nullptr, nullptr,
          bpj + l*D, x, nullptr, nullptr, nullptr, x, M, D, D, 0);
      ln_k<<<2048, 256, 0, stream>>>(x, ln2g + l*D, ln2b + l*D, hb);
    }
    gemm_bt<<<dim3(32, 16), 256, 0, stream>>>(hb, w1T + ((size_t)l << 22), nullptr, nullptr,
        b1 + (size_t)l*4*D, nullptr, m1, nullptr, nullptr, nullptr, M, 4*D, D, 1);
    gemm_splitk<<<dim3(8, 16, nz), 256, 0, stream>>>(m1, w2T + ((size_t)l << 22),
        pb, M, D, 4*D, 4*D / nz);
    const float* gn = (l < 7) ? (ln1g + (l+1)*D) : lnfg;
    const float* bn = (l < 7) ? (ln1b + (l+1)*D) : lnfb;
    reduce_ln_k<<<2048, 256, 0, stream>>>(x, pb, b2 + l*D, nz, gn, bn, hb);
  }
  gemm256_k<<<dim3(2000), 512, 0, stream>>>(hb, wlmT,
      blm, out, nullptr, M, 64000, D, 0);
}

// Round 14
// 1922.234 us; speedup vs baseline: 1.0251x; 1.0251x over previous
//
#include <hip/hip_runtime.h>

typedef __attribute__((ext_vector_type(8))) __bf16 bf16x8;
typedef __attribute__((ext_vector_type(4))) float f32x4;
typedef __attribute__((ext_vector_type(4))) unsigned int u32x4;
typedef __attribute__((ext_vector_type(2))) unsigned int u32x2;

__device__ __forceinline__ unsigned short f2bf(float f) {
  unsigned int u = __float_as_uint(f);
  u += 0x7fffu + ((u >> 16) & 1u);   // RNE
  return (unsigned short)(u >> 16);
}

__device__ __forceinline__ void gload16(const void* g, void* l) {
  __builtin_amdgcn_global_load_lds(
      (const __attribute__((address_space(1))) unsigned int*)g,
      (__attribute__((address_space(3))) unsigned int*)l, 16, 0, 0);
}

// ------------- fused embedding + LN (layer-0 LN1): x out f32, hb out bf16 ----
__global__ __launch_bounds__(256) void embed_ln_k(const int* __restrict__ idx,
    const float* __restrict__ tok, const float* __restrict__ pos,
    const float* __restrict__ g, const float* __restrict__ bta,
    float* __restrict__ x, unsigned short* __restrict__ out) {
  __shared__ float red[4];
  int row = blockIdx.x, tid = threadIdx.x;
  int t = row & 1023;
  int c = tid << 2;
  int id = idx[row];
  f32x4 xv = *(const f32x4*)(tok + ((size_t)id << 10) + c);
  f32x4 p = *(const f32x4*)(pos + ((size_t)t << 10) + c);
  xv += p;
  *(f32x4*)(x + ((size_t)row << 10) + c) = xv;
  float s = xv[0] + xv[1] + xv[2] + xv[3];
  #pragma unroll
  for (int off = 32; off; off >>= 1) s += __shfl_xor(s, off);
  if ((tid & 63) == 0) red[tid >> 6] = s;
  __syncthreads();
  float mean = (red[0] + red[1] + red[2] + red[3]) * (1.f / 1024.f);
  __syncthreads();
  f32x4 d = xv - mean;
  float s2 = d[0]*d[0] + d[1]*d[1] + d[2]*d[2] + d[3]*d[3];
  #pragma unroll
  for (int off = 32; off; off >>= 1) s2 += __shfl_xor(s2, off);
  if ((tid & 63) == 0) red[tid >> 6] = s2;
  __syncthreads();
  float var = (red[0] + red[1] + red[2] + red[3]) * (1.f / 1024.f);
  float rs = rsqrtf(var + 1e-5f);
  f32x4 gv = *(const f32x4*)(g + c);
  f32x4 bv = *(const f32x4*)(bta + c);
  unsigned int p0 = (unsigned int)f2bf(d[0]*rs*gv[0] + bv[0]) |
                    ((unsigned int)f2bf(d[1]*rs*gv[1] + bv[1]) << 16);
  unsigned int p1 = (unsigned int)f2bf(d[2]*rs*gv[2] + bv[2]) |
                    ((unsigned int)f2bf(d[3]*rs*gv[3] + bv[3]) << 16);
  u32x2 o; o[0] = p0; o[1] = p1;
  *(u32x2*)(out + ((size_t)row << 10) + c) = o;
}

// ---------------- layernorm (f32 in, bf16 out) — small-ws fallback ----------
__global__ __launch_bounds__(256) void ln_k(const float* __restrict__ x,
    const float* __restrict__ g, const float* __restrict__ bta,
    unsigned short* __restrict__ out) {
  __shared__ float red[4];
  int row = blockIdx.x, tid = threadIdx.x;
  const float* xr = x + ((size_t)row << 10);
  f32x4 xv = *(const f32x4*)(xr + (tid << 2));
  float s = xv[0] + xv[1] + xv[2] + xv[3];
  #pragma unroll
  for (int off = 32; off; off >>= 1) s += __shfl_xor(s, off);
  if ((tid & 63) == 0) red[tid >> 6] = s;
  __syncthreads();
  float mean = (red[0] + red[1] + red[2] + red[3]) * (1.f / 1024.f);
  __syncthreads();
  f32x4 d = xv - mean;
  float s2 = d[0]*d[0] + d[1]*d[1] + d[2]*d[2] + d[3]*d[3];
  #pragma unroll
  for (int off = 32; off; off >>= 1) s2 += __shfl_xor(s2, off);
  if ((tid & 63) == 0) red[tid >> 6] = s2;
  __syncthreads();
  float var = (red[0] + red[1] + red[2] + red[3]) * (1.f / 1024.f);
  float rs = rsqrtf(var + 1e-5f);
  f32x4 gv = *(const f32x4*)(g + (tid << 2));
  f32x4 bv = *(const f32x4*)(bta + (tid << 2));
  unsigned int p0 = (unsigned int)f2bf(d[0]*rs*gv[0] + bv[0]) |
                    ((unsigned int)f2bf(d[1]*rs*gv[1] + bv[1]) << 16);
  unsigned int p1 = (unsigned int)f2bf(d[2]*rs*gv[2] + bv[2]) |
                    ((unsigned int)f2bf(d[3]*rs*gv[3] + bv[3]) << 16);
  u32x2 o; o[0] = p0; o[1] = p1;
  *(u32x2*)(out + ((size_t)row << 10) + (tid << 2)) = o;
}

// ---------------- weight transpose: f32 [R][C] -> bf16 [C][R] ----------------
__global__ __launch_bounds__(256) void transp_k(const float* __restrict__ in,
    unsigned short* __restrict__ out, int R, int C) {
  __shared__ unsigned short tile[64 * 65];
  size_t lay = (size_t)blockIdx.z * R * C;
  int c0 = blockIdx.x << 6, r0 = blockIdx.y << 6;
  int t = threadIdx.x;
  #pragma unroll
  for (int i = 0; i < 4; i++) {
    int e = (i << 10) + (t << 2);
    int r = e >> 6, c = e & 63;
    f32x4 v = *(const f32x4*)(in + lay + (size_t)(r0 + r) * C + c0 + c);
    tile[r * 65 + c]     = f2bf(v[0]);
    tile[r * 65 + c + 1] = f2bf(v[1]);
    tile[r * 65 + c + 2] = f2bf(v[2]);
    tile[r * 65 + c + 3] = f2bf(v[3]);
  }
  __syncthreads();
  #pragma unroll
  for (int i = 0; i < 4; i++) {
    int e = (i << 10) + (t << 2);
    int cc = e >> 6, rr = e & 63;
    unsigned int a0 = tile[(rr + 0) * 65 + cc];
    unsigned int a1 = tile[(rr + 1) * 65 + cc];
    unsigned int a2 = tile[(rr + 2) * 65 + cc];
    unsigned int a3 = tile[(rr + 3) * 65 + cc];
    u32x2 pk; pk[0] = a0 | (a1 << 16); pk[1] = a2 | (a3 << 16);
    *(u32x2*)(out + lay + (size_t)(c0 + cc) * R + r0 + rr) = pk;
  }
}

// ---- batched 1024x1024 transpose: z = which*8 + layer (wq/wk/wv/wp) ----
__global__ __launch_bounds__(256) void transp4_k(
    const float* __restrict__ w0, const float* __restrict__ w1,
    const float* __restrict__ w2, const float* __restrict__ w3,
    unsigned short* __restrict__ o0, unsigned short* __restrict__ o1,
    unsigned short* __restrict__ o2, unsigned short* __restrict__ o3) {
  __shared__ unsigned short tile[64 * 65];
  int z = blockIdx.z;
  int which = z >> 3;
  size_t lay = (size_t)(z & 7) << 20;
  const float* in = which == 0 ? w0 : which == 1 ? w1 : which == 2 ? w2 : w3;
  unsigned short* out = which == 0 ? o0 : which == 1 ? o1 : which == 2 ? o2 : o3;
  int c0 = blockIdx.x << 6, r0 = blockIdx.y << 6;
  int t = threadIdx.x;
  #pragma unroll
  for (int i = 0; i < 4; i++) {
    int e = (i << 10) + (t << 2);
    int r = e >> 6, c = e & 63;
    f32x4 v = *(const f32x4*)(in + lay + (size_t)((r0 + r) << 10) + c0 + c);
    tile[r * 65 + c]     = f2bf(v[0]);
    tile[r * 65 + c + 1] = f2bf(v[1]);
    tile[r * 65 + c + 2] = f2bf(v[2]);
    tile[r * 65 + c + 3] = f2bf(v[3]);
  }
  __syncthreads();
  #pragma unroll
  for (int i = 0; i < 4; i++) {
    int e = (i << 10) + (t << 2);
    int cc = e >> 6, rr = e & 63;
    unsigned int a0 = tile[(rr + 0) * 65 + cc];
    unsigned int a1 = tile[(rr + 1) * 65 + cc];
    unsigned int a2 = tile[(rr + 2) * 65 + cc];
    unsigned int a3 = tile[(rr + 3) * 65 + cc];
    u32x2 pk; pk[0] = a0 | (a1 << 16); pk[1] = a2 | (a3 << 16);
    *(u32x2*)(out + lay + (size_t)((c0 + cc) << 10) + r0 + rr) = pk;
  }
}

// ============ 256x256 8-phase GEMM (round-8 proven: 396us, MfmaUtil 28%) ======
// BK=64, 128KB LDS, 1 block/CU. Frag-reuse quadrant path. PARKED.
#define VMC6 asm volatile("s_waitcnt vmcnt(6)" ::: "memory")
#define VMC8 asm volatile("s_waitcnt vmcnt(8)" ::: "memory")
#define VMC2 asm volatile("s_waitcnt vmcnt(2)" ::: "memory")
#define VMC0 asm volatile("s_waitcnt vmcnt(0)" ::: "memory")

__global__ __launch_bounds__(512, 2) void gemm256_k(
    const unsigned short* __restrict__ A, const unsigned short* __restrict__ Bt,
    const float* __restrict__ bias, float* __restrict__ o32,
    unsigned short* __restrict__ obf, int M, int N, int K, int relu) {
  __shared__ unsigned short lds[2][2][2][8192];
  int mb = M >> 8;
  int wg = blockIdx.x, nwg = gridDim.x;
  int cpx = nwg >> 3;
  int swz = (wg & 7) * cpx + (wg >> 3);      // nwg % 8 == 0
  int bm = swz % mb, bn = swz / mb;          // bm fast: per-XCD bn-stripes
  int m0 = bm << 8, n0 = bn << 8;
  int tid = threadIdx.x, lane = tid & 63, wave = tid >> 6;
  int wrow = wave >> 2, wcol = wave & 3;
  int lrow = lane & 15, g4 = lane >> 4, l7 = lane & 7;
  f32x4 acc[8][4] = {};
  bf16x8 af[8], bfv[4];
  const unsigned short* Ag = A + (size_t)m0 * K;
  const unsigned short* Bg = Bt + (size_t)n0 * K;
  auto stage = [&](int op, int b, int h, int kt) {
    const unsigned short* gb = (op ? Bg : Ag) + ((size_t)(h << 7)) * K + kt;
    char* lb = (char*)&lds[op][b][h][0];
    #pragma unroll
    for (int g = 0; g < 2; g++) {
      int row = (g << 6) + (wave << 3) + (lane >> 3);
      int klog = ((lane & 7) ^ ((lane >> 3) & 7)) << 3;   // shorts
      gload16(gb + (size_t)row * K + klog, lb + (g << 13) + (wave << 10));
    }
  };

#define PH(bi, qa, qb, LA, LB, STG, VM)                                        \
  {                                                                            \
    if (LA) {                                                                  \
      const unsigned short* Ah = &lds[0][bi][qa][0];                           \
      _Pragma("unroll")                                                        \
      for (int i = 0; i < 4; i++) {                                            \
        int rl = (wrow << 6) + (i << 4) + lrow;                                \
        af[i*2+0] = *(const bf16x8*)(Ah + rl * 64 + ((g4 ^ l7) << 3));         \
        af[i*2+1] = *(const bf16x8*)(Ah + rl * 64 + (((4 + g4) ^ l7) << 3));   \
      }                                                                        \
    }                                                                          \
    if (LB) {                                                                  \
      const unsigned short* Bh = &lds[1][bi][qb][0];                           \
      _Pragma("unroll")                                                        \
      for (int j = 0; j < 2; j++) {                                            \
        int cl = (wcol << 5) + (j << 4) + lrow;                                \
        bfv[j*2+0] = *(const bf16x8*)(Bh + cl * 64 + ((g4 ^ l7) << 3));        \
        bfv[j*2+1] = *(const bf16x8*)(Bh + cl * 64 + (((4 + g4) ^ l7) << 3));  \
      }                                                                        \
    }                                                                          \
    STG;                                                                       \
    __builtin_amdgcn_s_barrier();                                              \
    asm volatile("s_waitcnt lgkmcnt(0)" ::: "memory");                         \
    __builtin_amdgcn_sched_barrier(0);                                         \
    __builtin_amdgcn_s_setprio(1);                                             \
    _Pragma("unroll")                                                          \
    for (int i = 0; i < 4; i++)                                                \
      _Pragma("unroll")                                                        \
      for (int j = 0; j < 2; j++) {                                            \
        acc[(qa)*4+i][(qb)*2+j] = __builtin_amdgcn_mfma_f32_16x16x32_bf16(     \
            af[i*2+0], bfv[j*2+0], acc[(qa)*4+i][(qb)*2+j], 0, 0, 0);          \
        acc[(qa)*4+i][(qb)*2+j] = __builtin_amdgcn_mfma_f32_16x16x32_bf16(     \
            af[i*2+1], bfv[j*2+1], acc[(qa)*4+i][(qb)*2+j], 0, 0, 0);          \
      }                                                                        \
    __builtin_amdgcn_s_setprio(0);                                             \
    VM;                                                                        \
    __builtin_amdgcn_s_barrier();                                              \
  }

  int nt = K >> 6;          // K-tiles; nt even (K%128==0)
  int nit = nt >> 1;
  stage(0, 0, 0, 0); stage(1, 0, 0, 0); stage(1, 0, 1, 0); stage(0, 0, 1, 0);
  stage(0, 1, 0, 64);
  VMC2;
  __builtin_amdgcn_s_barrier();
  for (int it = 0; it < nit; ++it) {
    int kT1 = ((it << 1) + 1) << 6;
    int kT2 = ((it << 1) + 2) << 6;
    int kT3 = ((it << 1) + 3) << 6;
    bool m2 = (it + 1) < nit;
    PH(0, 0, 0, 1, 1, { stage(1, 1, 1, kT1); stage(1, 1, 0, kT1); }, )
    PH(0, 0, 1, 0, 1, { stage(0, 1, 1, kT1); }, )
    PH(0, 1, 1, 1, 0, if (m2) { stage(0, 0, 0, kT2); }, )
    PH(0, 1, 0, 0, 1, if (m2) { stage(1, 0, 1, kT2); },
       if (m2) { VMC6; } else { VMC2; })
    PH(1, 0, 0, 1, 1, if (m2) { stage(1, 0, 0, kT2); }, )
    PH(1, 0, 1, 0, 1, if (m2) { stage(0, 0, 1, kT2); },
       if (m2) { VMC8; } else { VMC0; })
    PH(1, 1, 1, 1, 0, if (m2) { stage(0, 1, 0, kT3); }, )
    PH(1, 1, 0, 0, 1, , if (m2) { VMC2; })
  }
#undef PH
  int frow = g4 << 2;
  #pragma unroll
  for (int rt = 0; rt < 8; rt++) {
    int qa = rt >> 2, i = rt & 3;
    int grow = m0 + (qa << 7) + (wrow << 6) + (i << 4) + frow;
    #pragma unroll
    for (int ct = 0; ct < 4; ct++) {
      int qb = ct >> 1, j = ct & 1;
      int gcol = n0 + (qb << 7) + (wcol << 5) + (j << 4) + lrow;
      float bb = bias ? bias[gcol] : 0.f;
      f32x4 av = acc[rt][ct];
      #pragma unroll
      for (int r = 0; r < 4; r++) {
        float vv = av[r] + bb;
        if (relu) vv = fmaxf(vv, 0.f);
        if (o32) o32[(size_t)(grow + r) * N + gcol] = vv;
        else obf[(size_t)(grow + r) * N + gcol] = f2bf(vv);
      }
    }
  }
}

// ---------------- m97-structure GEMM (layer GEMMs) ----------------
__global__ __launch_bounds__(256) void gemm_bt(
    const unsigned short* __restrict__ A,
    const unsigned short* __restrict__ Bt0, const unsigned short* __restrict__ Bt1,
    const unsigned short* __restrict__ Bt2,
    const float* __restrict__ bias, const float* resid,
    unsigned short* __restrict__ ob0, unsigned short* __restrict__ ob1,
    unsigned short* __restrict__ vtout, float* o32,
    int M, int N, int K, int relu) {
  __shared__ unsigned short As[128 * 64];
  __shared__ unsigned short Bs[128 * 64];
  int nbp = N >> 7;
  int which = blockIdx.x / nbp;
  int bx = blockIdx.x - which * nbp;
  const unsigned short* Bt = which == 0 ? Bt0 : (which == 1 ? Bt1 : Bt2);
  int m0 = blockIdx.y << 7, n0 = bx << 7;
  int tid = threadIdx.x, lane = tid & 63, wave = tid >> 6;
  int wr = (wave >> 1) << 6, wc = (wave & 1) << 6;
  int lrow = lane & 15, lk8 = (lane >> 4) << 3;
  int wbase = wave << 12;
  f32x4 acc[4][4] = {};
  const unsigned short* Ag = A + (size_t)m0 * K;
  const unsigned short* Bg = Bt + (size_t)n0 * K;
  for (int k0 = 0; k0 < K; k0 += 64) {
    #pragma unroll
    for (int i = 0; i < 4; i++) {
      int o = wbase + (i << 10) + (lane << 4);
      int r = o >> 7, c = (o & 127) >> 1;
      gload16(Ag + (size_t)r * K + k0 + c, (char*)As + wbase + (i << 10));
      gload16(Bg + (size_t)r * K + k0 + c, (char*)Bs + wbase + (i << 10));
    }
    __syncthreads();
    #pragma unroll
    for (int ks = 0; ks < 2; ks++) {
      bf16x8 af[4], bfv[4];
      #pragma unroll
      for (int i = 0; i < 4; i++)
        af[i] = *(const bf16x8*)(As + ((wr + (i << 4) + lrow) << 6) + (ks << 5) + lk8);
      #pragma unroll
      for (int i = 0; i < 4; i++)
        bfv[i] = *(const bf16x8*)(Bs + ((wc + (i << 4) + lrow) << 6) + (ks << 5) + lk8);
      #pragma unroll
      for (int mi = 0; mi < 4; mi++)
        #pragma unroll
        for (int ni = 0; ni < 4; ni++)
          acc[mi][ni] = __builtin_amdgcn_mfma_f32_16x16x32_bf16(af[mi], bfv[ni], acc[mi][ni], 0, 0, 0);
    }
    __syncthreads();
  }
  int fr = (lane >> 4) << 2;
  #pragma unroll
  for (int mi = 0; mi < 4; mi++) {
    #pragma unroll
    for (int ni = 0; ni < 4; ni++) {
      int row = m0 + wr + (mi << 4) + fr;
      int col = n0 + wc + (ni << 4) + lrow;
      f32x4 av = acc[mi][ni];
      if (bias) {
        float bb = bias[col];
        av[0] += bb; av[1] += bb; av[2] += bb; av[3] += bb;
      }
      if (relu) {
        av[0] = fmaxf(av[0], 0.f); av[1] = fmaxf(av[1], 0.f);
        av[2] = fmaxf(av[2], 0.f); av[3] = fmaxf(av[3], 0.f);
      }
      if (which == 2) {
        u32x2 pk;
        pk[0] = (unsigned int)f2bf(av[0]) | ((unsigned int)f2bf(av[1]) << 16);
        pk[1] = (unsigned int)f2bf(av[2]) | ((unsigned int)f2bf(av[3]) << 16);
        *(u32x2*)(vtout + (((size_t)(row >> 10) * 16 + (col >> 6)) * 64 + (col & 63)) * 1024
                  + (row & 1023)) = pk;
      } else if (o32) {
        #pragma unroll
        for (int r = 0; r < 4; r++) {
          size_t off = (size_t)(row + r) * N + col;
          float vvv = av[r];
          if (resid) vvv += resid[off];
          o32[off] = vvv;
        }
      } else {
        unsigned short* ob = which == 0 ? ob0 : ob1;
        #pragma unroll
        for (int r = 0; r < 4; r++)
          ob[(size_t)(row + r) * N + col] = f2bf(av[r]);
      }
    }
  }
}

// ---------------- split-K GEMM: partial f32, no epilogue ----------------
__global__ __launch_bounds__(256) void gemm_splitk(
    const unsigned short* __restrict__ A, const unsigned short* __restrict__ Bt,
    float* __restrict__ pbuf, int M, int N, int K, int KS) {
  __shared__ unsigned short As[128 * 64];
  __shared__ unsigned short Bs[128 * 64];
  int m0 = blockIdx.y << 7, n0 = blockIdx.x << 7;
  int kz = blockIdx.z * KS;
  int tid = threadIdx.x, lane = tid & 63, wave = tid >> 6;
  int wr = (wave >> 1) << 6, wc = (wave & 1) << 6;
  int lrow = lane & 15, lk8 = (lane >> 4) << 3;
  int wbase = wave << 12;
  f32x4 acc[4][4] = {};
  const unsigned short* Ag = A + (size_t)m0 * K;
  const unsigned short* Bg = Bt + (size_t)n0 * K;
  for (int k0 = kz; k0 < kz + KS; k0 += 64) {
    #pragma unroll
    for (int i = 0; i < 4; i++) {
      int o = wbase + (i << 10) + (lane << 4);
      int r = o >> 7, c = (o & 127) >> 1;
      gload16(Ag + (size_t)r * K + k0 + c, (char*)As + wbase + (i << 10));
      gload16(Bg + (size_t)r * K + k0 + c, (char*)Bs + wbase + (i << 10));
    }
    __syncthreads();
    #pragma unroll
    for (int ks = 0; ks < 2; ks++) {
      bf16x8 af[4], bfv[4];
      #pragma unroll
      for (int i = 0; i < 4; i++)
        af[i] = *(const bf16x8*)(As + ((wr + (i << 4) + lrow) << 6) + (ks << 5) + lk8);
      #pragma unroll
      for (int i = 0; i < 4; i++)
        bfv[i] = *(const bf16x8*)(Bs + ((wc + (i << 4) + lrow) << 6) + (ks << 5) + lk8);
      #pragma unroll
      for (int mi = 0; mi < 4; mi++)
        #pragma unroll
        for (int ni = 0; ni < 4; ni++)
          acc[mi][ni] = __builtin_amdgcn_mfma_f32_16x16x32_bf16(af[mi], bfv[ni], acc[mi][ni], 0, 0, 0);
    }
    __syncthreads();
  }
  int fr = (lane >> 4) << 2;
  float* pb = pbuf + (size_t)blockIdx.z * M * N;
  #pragma unroll
  for (int mi = 0; mi < 4; mi++)
    #pragma unroll
    for (int ni = 0; ni < 4; ni++) {
      int row = m0 + wr + (mi << 4) + fr;
      int col = n0 + wc + (ni << 4) + lrow;
      #pragma unroll
      for (int r = 0; r < 4; r++)
        pb[(size_t)(row + r) * N + col] = acc[mi][ni][r];
    }
}

// ---- fused: x += bias + sum_z pbuf[z]; out = LN(x_new) (bf16). N=1024 ----
__global__ __launch_bounds__(256) void reduce_ln_k(float* __restrict__ x,
    const float* __restrict__ pbuf, const float* __restrict__ bias, int nz,
    const float* __restrict__ g, const float* __restrict__ bta,
    unsigned short* __restrict__ out) {
  __shared__ float red[4];
  int row = blockIdx.x, tid = threadIdx.x;
  int c = tid << 2;
  size_t off = ((size_t)row << 10) + c;
  f32x4 s = *(const f32x4*)(bias + c);
  for (int z = 0; z < nz; z++)
    s += *(const f32x4*)(pbuf + ((size_t)z << 21) + off);
  f32x4 xv = *(const f32x4*)(x + off);
  xv += s;
  *(f32x4*)(x + off) = xv;
  float sm = xv[0] + xv[1] + xv[2] + xv[3];
  #pragma unroll
  for (int o = 32; o; o >>= 1) sm += __shfl_xor(sm, o);
  if ((tid & 63) == 0) red[tid >> 6] = sm;
  __syncthreads();
  float mean = (red[0] + red[1] + red[2] + red[3]) * (1.f / 1024.f);
  __syncthreads();
  f32x4 d = xv - mean;
  float s2 = d[0]*d[0] + d[1]*d[1] + d[2]*d[2] + d[3]*d[3];
  #pragma unroll
  for (int o = 32; o; o >>= 1) s2 += __shfl_xor(s2, o);
  if ((tid & 63) == 0) red[tid >> 6] = s2;
  __syncthreads();
  float var = (red[0] + red[1] + red[2] + red[3]) * (1.f / 1024.f);
  float rs = rsqrtf(var + 1e-5f);
  f32x4 gv = *(const f32x4*)(g + c);
  f32x4 bv = *(const f32x4*)(bta + c);
  unsigned int p0 = (unsigned int)f2bf(d[0]*rs*gv[0] + bv[0]) |
                    ((unsigned int)f2bf(d[1]*rs*gv[1] + bv[1]) << 16);
  unsigned int p1 = (unsigned int)f2bf(d[2]*rs*gv[2] + bv[2]) |
                    ((unsigned int)f2bf(d[3]*rs*gv[3] + bv[3]) << 16);
  u32x2 o2; o2[0] = p0; o2[1] = p1;
  *(u32x2*)(out + ((size_t)row << 10) + c) = o2;
}

// ------- windowed flash attention (round-12 proven version, defer-max REVERTED)
__global__ __launch_bounds__(256) void attn64_k(
    const unsigned short* __restrict__ q, const unsigned short* __restrict__ k,
    const unsigned short* __restrict__ vt, unsigned short* __restrict__ att) {
  __shared__ unsigned short Ks[2][64 * 72];  // [buf][s][hd]
  __shared__ unsigned short Vs[2][64 * 72];  // [buf][hd][s]
  __shared__ unsigned short Ps[4][16 * 72];  // per-wave [row][s]
  int t0 = (15 - (int)blockIdx.x) << 6;      // LPT: heavy blocks first
  int h = blockIdx.y, b = blockIdx.z;
  int tid = threadIdx.x, lane = tid & 63, w = tid >> 6;
  int lrow = lane & 15, lk8 = (lane >> 4) << 3, fr = (lane >> 4) << 2;
  int qrow = t0 + (w << 4) + lrow;
  size_t qoff = ((size_t)((b << 10) + qrow) << 10) + (h << 6);
  bf16x8 a0 = *(const bf16x8*)(q + qoff + lk8);
  bf16x8 a1 = *(const bf16x8*)(q + qoff + 32 + lk8);
  float m_[4] = {-1e30f, -1e30f, -1e30f, -1e30f};
  float l_[4] = {0.f, 0.f, 0.f, 0.f};
  f32x4 o_[4] = {};
  int s_lo = (511 - ((t0 + 63) >> 1)) & ~63;
  int s_hi = 511 + ((t0 + 64) >> 1);
  int s_end = (s_hi + 64) & ~63;             // exclusive, <=1024
  int krow = tid >> 2, kc = (tid & 3) << 4;  // 4 thr/row, 16 shorts each
  size_t vbase = ((size_t)((b << 4) + h) << 16) + ((size_t)krow << 10);
  unsigned short* Psw = &Ps[w][0];
  u32x4 kv0, kv1, vv0, vv1;
  auto loadT = [&](int s0) {
    size_t koff = (((size_t)((b << 10) + s0 + krow)) << 10) + (h << 6) + kc;
    kv0 = *(const u32x4*)(k + koff);
    kv1 = *(const u32x4*)(k + koff + 8);
    vv0 = *(const u32x4*)(vt + vbase + s0 + kc);
    vv1 = *(const u32x4*)(vt + vbase + s0 + kc + 8);
  };
  loadT(s_lo);
  int buf = 0;
  for (int s0 = s_lo; s0 < s_end; s0 += 64) {
    unsigned short* Kb = &Ks[buf][0];
    unsigned short* Vb = &Vs[buf][0];
    *(u32x4*)(Kb + krow * 72 + kc) = kv0;
    *(u32x4*)(Kb + krow * 72 + kc + 8) = kv1;
    *(u32x4*)(Vb + krow * 72 + kc) = vv0;
    *(u32x4*)(Vb + krow * 72 + kc + 8) = vv1;
    __syncthreads();
    if (s0 + 64 < s_end) loadT(s0 + 64);     // overlap with compute below
    f32x4 sc[4];
    #pragma unroll
    for (int sb = 0; sb < 4; sb++) {
      f32x4 z = {};
      bf16x8 kb0 = *(const bf16x8*)(Kb + ((sb << 4) + lrow) * 72 + lk8);
      bf16x8 kb1 = *(const bf16x8*)(Kb + ((sb << 4) + lrow) * 72 + 32 + lk8);
      z = __builtin_amdgcn_mfma_f32_16x16x32_bf16(a0, kb0, z, 0, 0, 0);
      z = __builtin_amdgcn_mfma_f32_16x16x32_bf16(a1, kb1, z, 0, 0, 0);
      sc[sb] = z;
    }
    #pragma unroll
    for (int r = 0; r < 4; r++) {
      int t = t0 + (w << 4) + fr + r;
      int lov = 511 - (t >> 1), hiv = 511 + ((t + 1) >> 1);
      float px[4];
      float tm = -1e30f;
      #pragma unroll
      for (int sb = 0; sb < 4; sb++) {
        int sX = s0 + (sb << 4) + lrow;
        bool vX = (sX >= lov) && (sX <= hiv);
        float x = vX ? sc[sb][r] * 0.125f : -1e30f;
        px[sb] = x;
        tm = fmaxf(tm, x);
      }
      #pragma unroll
      for (int off = 8; off; off >>= 1) tm = fmaxf(tm, __shfl_xor(tm, off));
      float nm = fmaxf(m_[r], tm);
      float sca = __expf(m_[r] - nm);
      m_[r] = nm;
      float ps = 0.f;
      #pragma unroll
      for (int sb = 0; sb < 4; sb++) {
        float pv = __expf(px[sb] - nm);   // invalid -> exp(-inf) = 0
        ps += pv;
        Psw[(fr + r) * 72 + (sb << 4) + lrow] = f2bf(pv);
      }
      #pragma unroll
      for (int off = 8; off; off >>= 1) ps += __shfl_xor(ps, off);
      l_[r] = l_[r] * sca + ps;
      #pragma unroll
      for (int nb = 0; nb < 4; nb++) o_[nb][r] *= sca;
    }
    bf16x8 pa0 = *(const bf16x8*)(Psw + lrow * 72 + lk8);
    bf16x8 pa1 = *(const bf16x8*)(Psw + lrow * 72 + 32 + lk8);
    #pragma unroll
    for (int nb = 0; nb < 4; nb++) {
      bf16x8 vb0 = *(const bf16x8*)(Vb + ((nb << 4) + lrow) * 72 + lk8);
      bf16x8 vb1 = *(const bf16x8*)(Vb + ((nb << 4) + lrow) * 72 + 32 + lk8);
      o_[nb] = __builtin_amdgcn_mfma_f32_16x16x32_bf16(pa0, vb0, o_[nb], 0, 0, 0);
      o_[nb] = __builtin_amdgcn_mfma_f32_16x16x32_bf16(pa1, vb1, o_[nb], 0, 0, 0);
    }
    buf ^= 1;
  }
  #pragma unroll
  for (int nb = 0; nb < 4; nb++)
    #pragma unroll
    for (int r = 0; r < 4; r++) {
      float ov = o_[nb][r] / l_[r];
      att[((size_t)((b << 10) + t0 + (w << 4) + fr + r) << 10) + (h << 6) + (nb << 4) + lrow]
          = f2bf(ov);
    }
}

extern "C" void kernel_launch(void* const* d_in, const int* in_sizes, int n_in,
                              void* d_out, int out_size, void* d_ws, size_t ws_size,
                              hipStream_t stream) {
  (void)in_sizes; (void)n_in; (void)out_size;
  const int*   idx  = (const int*)d_in[0];
  const float* tok  = (const float*)d_in[1];
  const float* pos  = (const float*)d_in[2];
  const float* ln1g = (const float*)d_in[3];
  const float* ln1b = (const float*)d_in[4];
  const float* wq   = (const float*)d_in[5];
  const float* wk   = (const float*)d_in[6];
  const float* wv   = (const float*)d_in[7];
  const float* wpj  = (const float*)d_in[8];
  const float* bpj  = (const float*)d_in[9];
  const float* ln2g = (const float*)d_in[10];
  const float* ln2b = (const float*)d_in[11];
  const float* w1   = (const float*)d_in[12];
  const float* b1   = (const float*)d_in[13];
  const float* w2   = (const float*)d_in[14];
  const float* b2   = (const float*)d_in[15];
  const float* lnfg = (const float*)d_in[16];
  const float* lnfb = (const float*)d_in[17];
  const float* wlm  = (const float*)d_in[18];
  const float* blm  = (const float*)d_in[19];
  float* out = (float*)d_out;

  char* ws = (char*)d_ws;
  const size_t MB = 1u << 20;
  float*          x    = (float*)ws;
  unsigned short* hb   = (unsigned short*)(ws + 8 * MB);
  unsigned short* qb   = (unsigned short*)(ws + 12 * MB);
  unsigned short* kb   = (unsigned short*)(ws + 16 * MB);
  unsigned short* vbuf = (unsigned short*)(ws + 20 * MB);
  unsigned short* ab   = (unsigned short*)(ws + 24 * MB);
  unsigned short* m1   = (unsigned short*)(ws + 28 * MB);
  const int M = 2048, D = 1024;

  int nz; float* pb; bool bigp;
  if (ws_size >= 408 * MB) { nz = 4; pb = (float*)(ws + 376 * MB); bigp = true; }
  else                     { nz = 2; pb = (float*)(ws + 12 * MB); bigp = false; }

  unsigned short* wqT  = (unsigned short*)(ws + 44 * MB);
  unsigned short* wkT  = (unsigned short*)(ws + 60 * MB);
  unsigned short* wvT  = (unsigned short*)(ws + 76 * MB);
  unsigned short* wpT  = (unsigned short*)(ws + 92 * MB);
  unsigned short* w1T  = (unsigned short*)(ws + 108 * MB);
  unsigned short* w2T  = (unsigned short*)(ws + 172 * MB);
  unsigned short* wlmT = (unsigned short*)(ws + 236 * MB);
  transp4_k<<<dim3(16, 16, 32), 256, 0, stream>>>(wq, wk, wv, wpj,
      wqT, wkT, wvT, wpT);
  transp_k<<<dim3(64, 16, 8), 256, 0, stream>>>(w1,   w1T,  1024, 4096);
  transp_k<<<dim3(16, 64, 8), 256, 0, stream>>>(w2,   w2T,  4096, 1024);
  transp_k<<<dim3(1000, 16, 1), 256, 0, stream>>>(wlm, wlmT, 1024, 64000);

  embed_ln_k<<<2048, 256, 0, stream>>>(idx, tok, pos, ln1g, ln1b, x, hb);
  for (int l = 0; l < 8; l++) {
    size_t wo = (size_t)l << 20;
    gemm_bt<<<dim3(24, 16), 256, 0, stream>>>(hb, wqT + wo, wkT + wo, wvT + wo,
        nullptr, nullptr, qb, kb, vbuf, nullptr, M, D, D, 0);
    attn64_k<<<dim3(16, 16, 2), 256, 0, stream>>>(qb, kb, vbuf, ab);
    if (bigp) {
      // proj split-K x4 (512 blocks = 2/CU) + fused reduce+LN2
      gemm_splitk<<<dim3(8, 16, 4), 256, 0, stream>>>(ab, wpT + wo,
          pb, M, D, D, D / 4);
      reduce_ln_k<<<2048, 256, 0, stream>>>(x, pb, bpj + l*D, 4,
          ln2g + l*D, ln2b + l*D, hb);
    } else {
      gemm_bt<<<dim3(8, 16), 256, 0, stream>>>(ab, wpT + wo, nullptr, nullptr,
          bpj + l*D, x, nullptr, nullptr, nullptr, x, M, D, D, 0);
      ln_k<<<2048, 256, 0, stream>>>(x, ln2g + l*D, ln2b + l*D, hb);
    }
    gemm_bt<<<dim3(32, 16), 256, 0, stream>>>(hb, w1T + ((size_t)l << 22), nullptr, nullptr,
        b1 + (size_t)l*4*D, nullptr, m1, nullptr, nullptr, nullptr, M, 4*D, D, 1);
    gemm_splitk<<<dim3(8, 16, nz), 256, 0, stream>>>(m1, w2T + ((size_t)l << 22),
        pb, M, D, 4*D, 4*D / nz);
    const float* gn = (l < 7) ? (ln1g + (l+1)*D) : lnfg;
    const float* bn = (l < 7) ? (ln1b + (l+1)*D) : lnfb;
    reduce_ln_k<<<2048, 256, 0, stream>>>(x, pb, b2 + l*D, nz, gn, bn, hb);
  }
  gemm256_k<<<dim3(2000), 512, 0, stream>>>(hb, wlmT,
      blm, out, nullptr, M, 64000, D, 0);
}